// Round 12
// baseline (169.347 us; speedup 1.0000x reference)
//
#include <hip/hip_runtime.h>
#include <stdint.h>

typedef unsigned short u16;
typedef __bf16 bf16x8 __attribute__((ext_vector_type(8)));
typedef float f32x4 __attribute__((ext_vector_type(4)));

#define M_PIX 12544   // 4*56*56 pixels
#define DIMC  512
#define NQKV  1536

static __device__ __forceinline__ u16 f2bf(float f) {
  union { float f; uint32_t u; } x; x.f = f;
  uint32_t r = x.u + 0x7FFFu + ((x.u >> 16) & 1u);
  return (u16)(r >> 16);
}

// ---- cast W only: Wq|Wk|Wv -> Wc[1536][512] bf16 (X cast fused into gemm) ----
__global__ void cast_w(const float* __restrict__ Wq, const float* __restrict__ Wk,
                       const float* __restrict__ Wv, u16* __restrict__ Wc) {
  int wi = (blockIdx.x * 256 + threadIdx.x) * 4;
  if (wi >= NQKV * DIMC) return;
  int r = wi >> 9;
  int c = wi & 511;
  const float* src = (r < 512)  ? (Wq + (size_t)r * 512 + c)
                   : (r < 1024) ? (Wk + (size_t)(r - 512) * 512 + c)
                                : (Wv + (size_t)(r - 1024) * 512 + c);
  float4 f = *(const float4*)src;
  uint32_t p0 = (uint32_t)f2bf(f.x) | ((uint32_t)f2bf(f.y) << 16);
  uint32_t p1 = (uint32_t)f2bf(f.z) | ((uint32_t)f2bf(f.w) << 16);
  *(uint2*)(Wc + wi) = make_uint2(p0, p1);
}

// ---- R21 (= R20 resubmit): fused QKV GEMM, A = X fp32 read DIRECTLY.
// A-staging: per chunk read 2 float4 (coalesced: 4 adj threads = 128B),
// v_cvt_pk_bf16_f32 x4, ds_write_b128 to the SWIZZLED slot
// ((c&3) ^ f(row)), f(row) = (row>>1)&3 — identical involution to R19's
// pre-swizzled-source form, so the verified read side (sw8) is unchanged.
// B-staging: unchanged global_load_lds from bf16 Wc.
// XCD A-panel clustering kept (12 n-sharers of each m-panel adjacent/XCD).
__global__ __launch_bounds__(256, 4) void gemm_qkv(
    const float* __restrict__ X, const u16* __restrict__ Bm,
    const float* __restrict__ bq, const float* __restrict__ bk,
    const float* __restrict__ bv, u16* __restrict__ qkv) {
  __shared__ u16 sA[2][128 * 32];
  __shared__ u16 sB[2][128 * 32];
  const int t = threadIdx.x;
  const int lane = t & 63;
  const int w = t >> 6;
  const int bid = blockIdx.x;
  const int g = (bid & 7) * 147 + (bid >> 3);   // bijective: 1176 = 8*147
  const int tile_m = (g / 12) * 128;
  const int tile_n = (g % 12) * 128;
  const int wm = (w & 1) * 64;
  const int wn = (w >> 1) * 64;
  const int quad = lane >> 4;
  const int l16 = lane & 15;

  f32x4 acc[4][4];
#pragma unroll
  for (int a = 0; a < 4; ++a)
#pragma unroll
    for (int bb = 0; bb < 4; ++bb) acc[a][bb] = (f32x4){0.f, 0.f, 0.f, 0.f};

  const int c0 = t, c1 = t + 256;
  const int r0 = c0 >> 2, j0c = c0 & 3;
  const int r1 = c1 >> 2, j1c = c1 & 3;
  const int s0 = j0c ^ ((c0 >> 3) & 3);          // dest slot = src ^ f(r0)
  const int s1 = j1c ^ ((c1 >> 3) & 3);
  // A source: LINEAR fp32 columns (coalesced); B source: swizzled bf16 col
  const float* gX0 = X + (size_t)(tile_m + r0) * DIMC + j0c * 8;
  const float* gX1 = X + (size_t)(tile_m + r1) * DIMC + j1c * 8;
  const int ko0 = s0 * 8, ko1 = s1 * 8;          // B keeps R19 pre-swizzled src
  const u16* gB0 = Bm + (size_t)(tile_n + r0) * DIMC + ko0;
  const u16* gB1 = Bm + (size_t)(tile_n + r1) * DIMC + ko1;
  const int ldsoff = (t & ~63) * 8;   // wave-uniform base; HW adds lane*16B
  u16* const dA0 = (u16*)sA[0] + r0 * 32 + s0 * 8;   // +h*4096 u16 selects sA[h]
  u16* const dA1 = (u16*)sA[0] + r1 * 32 + s1 * 8;
  const int halfStride = 128 * 32;                   // u16 elems per sA buffer

  for (int k0 = 0; k0 < DIMC; k0 += 64) {
#pragma unroll
    for (int h = 0; h < 2; ++h) {
      // ---- A: fp32 -> bf16 in-flight ----
      float4 xa0 = *(const float4*)(gX0 + k0 + h * 32);
      float4 xb0 = *(const float4*)(gX0 + k0 + h * 32 + 4);
      float4 xa1 = *(const float4*)(gX1 + k0 + h * 32);
      float4 xb1 = *(const float4*)(gX1 + k0 + h * 32 + 4);
      uint32_t w0, w1, w2, w3, y0, y1, y2, y3;
      asm("v_cvt_pk_bf16_f32 %0, %1, %2" : "=v"(w0) : "v"(xa0.x), "v"(xa0.y));
      asm("v_cvt_pk_bf16_f32 %0, %1, %2" : "=v"(w1) : "v"(xa0.z), "v"(xa0.w));
      asm("v_cvt_pk_bf16_f32 %0, %1, %2" : "=v"(w2) : "v"(xb0.x), "v"(xb0.y));
      asm("v_cvt_pk_bf16_f32 %0, %1, %2" : "=v"(w3) : "v"(xb0.z), "v"(xb0.w));
      asm("v_cvt_pk_bf16_f32 %0, %1, %2" : "=v"(y0) : "v"(xa1.x), "v"(xa1.y));
      asm("v_cvt_pk_bf16_f32 %0, %1, %2" : "=v"(y1) : "v"(xa1.z), "v"(xa1.w));
      asm("v_cvt_pk_bf16_f32 %0, %1, %2" : "=v"(y2) : "v"(xb1.x), "v"(xb1.y));
      asm("v_cvt_pk_bf16_f32 %0, %1, %2" : "=v"(y3) : "v"(xb1.z), "v"(xb1.w));
      *(uint4*)(dA0 + h * halfStride) = make_uint4(w0, w1, w2, w3);
      *(uint4*)(dA1 + h * halfStride) = make_uint4(y0, y1, y2, y3);
      // ---- B: async global->LDS (unchanged) ----
      __builtin_amdgcn_global_load_lds(
          (const __attribute__((address_space(1))) void*)(gB0 + k0 + h * 32),
          (__attribute__((address_space(3))) void*)(sB[h] + 0 * 2048 + ldsoff), 16, 0, 0);
      __builtin_amdgcn_global_load_lds(
          (const __attribute__((address_space(1))) void*)(gB1 + k0 + h * 32),
          (__attribute__((address_space(3))) void*)(sB[h] + 1 * 2048 + ldsoff), 16, 0, 0);
    }
    __syncthreads();

    const int sw8 = (quad ^ ((l16 >> 1) & 3)) * 8;   // swizzled read slot (R19)
#pragma unroll
    for (int h = 0; h < 2; ++h) {
      bf16x8 af[4], bfr[4];
#pragma unroll
      for (int mt = 0; mt < 4; ++mt)
        af[mt] = *(const bf16x8*)(sA[h] + (wm + mt * 16 + l16) * 32 + sw8);
#pragma unroll
      for (int nt = 0; nt < 4; ++nt)
        bfr[nt] = *(const bf16x8*)(sB[h] + (wn + nt * 16 + l16) * 32 + sw8);
#pragma unroll
      for (int mt = 0; mt < 4; ++mt)
#pragma unroll
        for (int nt = 0; nt < 4; ++nt)
          acc[mt][nt] = __builtin_amdgcn_mfma_f32_16x16x32_bf16(bfr[nt], af[mt], acc[mt][nt], 0, 0, 0);
    }
    __syncthreads();
  }

  const float qscale = 0.17677669529663687f;  // 1/sqrt(32)
#pragma unroll
  for (int mt = 0; mt < 4; ++mt) {
    const int m = tile_m + wm + mt * 16 + l16;
#pragma unroll
    for (int nt = 0; nt < 4; ++nt) {
      const int n0 = tile_n + wn + nt * 16 + quad * 4;
      const int mat = n0 >> 9;
      const int cc = n0 & 511;
      const float* bias = (mat == 0) ? bq : (mat == 1) ? bk : bv;
      const float4 bv4 = *(const float4*)(bias + cc);
      const float scl = (mat == 0) ? qscale : 1.0f;
      u16 h0 = f2bf((acc[mt][nt][0] + bv4.x) * scl);
      u16 h1 = f2bf((acc[mt][nt][1] + bv4.y) * scl);
      u16 h2 = f2bf((acc[mt][nt][2] + bv4.z) * scl);
      u16 h3 = f2bf((acc[mt][nt][3] + bv4.w) * scl);
      uint2 pk = make_uint2((uint32_t)h0 | ((uint32_t)h1 << 16),
                            (uint32_t)h2 | ((uint32_t)h3 << 16));
      *(uint2*)(qkv + (size_t)mat * M_PIX * DIMC + (size_t)m * DIMC + cc) = pk;
    }
  }
}

// ---- neighborhood attention v12 (unchanged, best-known). ----
__global__ __launch_bounds__(512, 4) void natten_k(const u16* __restrict__ qkv,
                                                   const float* __restrict__ rpb,
                                                   float* __restrict__ out) {
  __shared__ u16 sP[8 * 2688];       // 43008 B, per-wave P tiles (PRIVATE per wave)
  __shared__ u16 sVt[32 * 296];      // 18944 B, [dim][cand], stride 296 u16
  __shared__ float sRpb[256];        // 169 real (pre-scaled by LOG2E) + zero pad
  __shared__ uint32_t sTbl[320];     // [parity][160]: c | (r'*13+c)<<8 ; 255 = invalid

  const int tid = threadIdx.x;
  const int lane = tid & 63;
  const int w = tid >> 6;            // 0..7: pixel row within block
  const int l16 = lane & 15;
  const int quad = lane >> 4;

  const int bid = blockIdx.x;
  const int xcd = bid & 7;
  const int idx = bid >> 3;          // 0..223
  const int head = idx / 14;
  const int gl = idx - head * 14;
  const int g = xcd * 14 + gl;       // 0..111
  const int jg = g & 3;
  const int gi = g >> 2;             // 0..27
  const int b = gi / 7;
  const int ig = gi - b * 7;
  const int i0 = ig * 8, j0 = jg * 14;
  int c0 = j0 - 3; c0 = c0 < 0 ? 0 : (c0 > 36 ? 36 : c0);
  int nib = i0 - 3; nib = nib < 0 ? 0 : (nib > 49 ? 49 : nib);

  const int iw = i0 + w;
  int niw = iw - 3; niw = niw < 0 ? 0 : (niw > 49 ? 49 : niw);
  const int rowoff = niw - nib;       // 0..7
  const int par = rowoff & 1;
  const int woff2 = rowoff * 20 - par * 4;   // 16B-aligned cand base, 0..136
  const int wconst = niw - iw + 6;

  const int qv = l16 < 14 ? l16 : 13;        // clamp pad queries for safe rpb idx
  const int jq = j0 + qv;
  int njq = jq - 3; njq = njq < 0 ? 0 : (njq > 49 ? 49 : njq);
  const uint32_t offq = (uint32_t)(njq - c0); // 0..13
  const int Cq = wconst * 13 + (c0 - jq + 6);

  const u16* Kpl = qkv + (size_t)M_PIX * DIMC;

  union { uint4 u; bf16x8 v; } qu;
  qu.u = make_uint4(0, 0, 0, 0);
  if (l16 < 14) {
    size_t qpx = (size_t)((b * 56 + iw) * 56 + j0 + l16);
    qu.u = *(const uint4*)(qkv + qpx * DIMC + head * 32 + quad * 8);
  }
  const bf16x8 qf = qu.v;

  if (tid < 296) {
    const int pair = tid >> 1, half = tid & 1;
    const int cand0 = pair * 2;
    int r = (cand0 * 205) >> 12;
    int c = cand0 - r * 20;
    int rimg = nib + r;
    const bool ok = (rimg < 56);
    size_t px = (size_t)((b * 56 + rimg) * 56 + c0 + c);
    const u16* vsrc = Kpl + (size_t)M_PIX * DIMC + px * DIMC + head * 32 + half * 16;
    u16* vt = sVt + cand0;
#pragma unroll
    for (int dgh = 0; dgh < 2; ++dgh) {
      uint4 va = ok ? *(const uint4*)(vsrc + dgh * 8) : make_uint4(0, 0, 0, 0);
      uint4 vb = ok ? *(const uint4*)(vsrc + DIMC + dgh * 8) : make_uint4(0, 0, 0, 0);
      int d0 = (half * 2 + dgh) * 8;
      *(uint32_t*)(vt + (d0 + 0) * 296) = __builtin_amdgcn_perm(vb.x, va.x, 0x05040100u);
      *(uint32_t*)(vt + (d0 + 1) * 296) = __builtin_amdgcn_perm(vb.x, va.x, 0x07060302u);
      *(uint32_t*)(vt + (d0 + 2) * 296) = __builtin_amdgcn_perm(vb.y, va.y, 0x05040100u);
      *(uint32_t*)(vt + (d0 + 3) * 296) = __builtin_amdgcn_perm(vb.y, va.y, 0x07060302u);
      *(uint32_t*)(vt + (d0 + 4) * 296) = __builtin_amdgcn_perm(vb.z, va.z, 0x05040100u);
      *(uint32_t*)(vt + (d0 + 5) * 296) = __builtin_amdgcn_perm(vb.z, va.z, 0x07060302u);
      *(uint32_t*)(vt + (d0 + 6) * 296) = __builtin_amdgcn_perm(vb.w, va.w, 0x05040100u);
      *(uint32_t*)(vt + (d0 + 7) * 296) = __builtin_amdgcn_perm(vb.w, va.w, 0x07060302u);
    }
  }
  const float LOG2E = 1.4426950408889634f;
  if (tid < 256) sRpb[tid] = (tid < 169) ? rpb[head * 169 + tid] * LOG2E : 0.f;
  if (tid < 320) {
    int pp = tid >= 160 ? 1 : 0;
    int s = tid - pp * 160;
    int t0 = s - pp * 4;
    uint32_t e = 255u;
    if (t0 >= 0 && t0 < 140) {
      int r = (t0 * 205) >> 12;
      int c = t0 - r * 20;
      e = (uint32_t)c | ((uint32_t)(r * 13 + c) << 8);
    }
    sTbl[tid] = e;
  }

  const int pxbase = (b * 56 + nib) * 56 + c0;   // cand(r,c) -> px = pxbase + r*56 + c
  const u16* kbase = Kpl + (size_t)head * 32 + quad * 8;
  bf16x8 kreg[9];
#pragma unroll
  for (int ch = 0; ch < 9; ++ch) {
    int cand = woff2 + ch * 16 + l16;
    int r = (cand * 205) >> 12;                  // cand/20, exact for cand<409
    int c = cand - r * 20;
    int px = pxbase + r * 56 + c;                // pad rows: in-allocation garbage, masked
    kreg[ch] = *(const bf16x8*)(kbase + (size_t)px * DIMC);
  }

  __syncthreads();   // publish sVt/sRpb/sTbl; K loads still in flight

  u16* sPw = sP + w * 2688;
  f32x4 S[9];
  __builtin_amdgcn_s_setprio(1);
#pragma unroll
  for (int ch = 0; ch < 9; ++ch)
    S[ch] = __builtin_amdgcn_mfma_f32_16x16x32_bf16(kreg[ch], qf, (f32x4){0.f, 0.f, 0.f, 0.f}, 0, 0, 0);
  __builtin_amdgcn_s_setprio(0);

  float l = 0.f;
  const uint32_t* tb = sTbl + par * 160;
#pragma unroll
  for (int ch = 0; ch < 9; ++ch) {
    uint4 te = *(const uint4*)(tb + ch * 16 + quad * 4);
    float pv[4];
    uint32_t es[4] = {te.x, te.y, te.z, te.w};
#pragma unroll
    for (int rg = 0; rg < 4; ++rg) {
      uint32_t e = es[rg];
      uint32_t ce = e & 255u;
      bool valid = (ce - offq) < 7u;           // unsigned window test
      int ridx = (int)((e >> 8) & 255u) + Cq;  // invalid -> Cq (pad zero, safe)
      float rbl = sRpb[ridx];                  // pre-scaled by LOG2E
      float p = exp2f(__builtin_fmaf(S[ch][rg], LOG2E, rbl));
      p = valid ? p : 0.f;
      pv[rg] = p;
      l += p;
    }
    uint32_t plo, phi;
    asm("v_cvt_pk_bf16_f32 %0, %1, %2" : "=v"(plo) : "v"(pv[0]), "v"(pv[1]));
    asm("v_cvt_pk_bf16_f32 %0, %1, %2" : "=v"(phi) : "v"(pv[2]), "v"(pv[3]));
    *(uint2*)((char*)sPw + l16 * 336 + ch * 32 + quad * 8) = make_uint2(plo, phi);
  }
  *(uint2*)((char*)sPw + l16 * 336 + 9 * 32 + quad * 8) = make_uint2(0u, 0u);
  l += __shfl_xor(l, 16);
  l += __shfl_xor(l, 32);

  asm volatile("s_waitcnt lgkmcnt(0)" ::: "memory");
  __builtin_amdgcn_sched_barrier(0);

  f32x4 O0 = (f32x4){0.f, 0.f, 0.f, 0.f};
  f32x4 O1 = (f32x4){0.f, 0.f, 0.f, 0.f};
  __builtin_amdgcn_s_setprio(1);
#pragma unroll
  for (int c32 = 0; c32 < 5; ++c32) {
    bf16x8 pf = *(const bf16x8*)((char*)sPw + l16 * 336 + c32 * 64 + quad * 16);
    bf16x8 v0 = *(const bf16x8*)((char*)sVt + (0 + l16) * 592 + woff2 * 2 + c32 * 64 + quad * 16);
    bf16x8 v1 = *(const bf16x8*)((char*)sVt + (16 + l16) * 592 + woff2 * 2 + c32 * 64 + quad * 16);
    O0 = __builtin_amdgcn_mfma_f32_16x16x32_bf16(v0, pf, O0, 0, 0, 0);
    O1 = __builtin_amdgcn_mfma_f32_16x16x32_bf16(v1, pf, O1, 0, 0, 0);
  }
  __builtin_amdgcn_s_setprio(0);

  if (l16 < 14) {
    const float inv = __builtin_amdgcn_rcpf(l);   // bf16-level tolerance: rcp safe
    float* op = out + ((size_t)((b * 56 + iw) * 56 + j0 + l16)) * DIMC + head * 32;
    *(float4*)(op + quad * 4) =
        make_float4(O0[0] * inv, O0[1] * inv, O0[2] * inv, O0[3] * inv);
    *(float4*)(op + 16 + quad * 4) =
        make_float4(O1[0] * inv, O1[1] * inv, O1[2] * inv, O1[3] * inv);
  }
}

extern "C" void kernel_launch(void* const* d_in, const int* in_sizes, int n_in,
                              void* d_out, int out_size, void* d_ws, size_t ws_size,
                              hipStream_t stream) {
  const float* x   = (const float*)d_in[0];
  const float* Wq  = (const float*)d_in[1];
  const float* bq  = (const float*)d_in[2];
  const float* Wk  = (const float*)d_in[3];
  const float* bk  = (const float*)d_in[4];
  const float* Wv  = (const float*)d_in[5];
  const float* bv  = (const float*)d_in[6];
  const float* rpb = (const float*)d_in[7];
  float* out = (float*)d_out;

  u16* Wc  = (u16*)d_ws;
  u16* qkv = Wc + (size_t)NQKV * DIMC;

  const int ncast = (NQKV * DIMC) / 4;
  cast_w<<<(ncast + 255) / 256, 256, 0, stream>>>(Wq, Wk, Wv, Wc);
  gemm_qkv<<<1176, 256, 0, stream>>>(x, Wc, bq, bk, bv, qkv);   // X fp32 direct, fused cast
  natten_k<<<1792, 512, 0, stream>>>(qkv, rpb, out);            // v12 (unchanged)
}

// Round 13
// 147.336 us; speedup vs baseline: 1.1494x; 1.1494x over previous
//
#include <hip/hip_runtime.h>
#include <stdint.h>

typedef unsigned short u16;
typedef __bf16 bf16x8 __attribute__((ext_vector_type(8)));
typedef float f32x4 __attribute__((ext_vector_type(4)));

#define M_PIX 12544   // 4*56*56 pixels
#define DIMC  512
#define NQKV  1536

static __device__ __forceinline__ u16 f2bf(float f) {
  union { float f; uint32_t u; } x; x.f = f;
  uint32_t r = x.u + 0x7FFFu + ((x.u >> 16) & 1u);
  return (u16)(r >> 16);
}

// ---- fused cast: X (fp32->bf16) then Wq|Wk|Wv -> Wc[1536][512] ----
// R21 lesson: one-shot cast amortized over the gemm's 12 A-panel re-reads
// beats in-gemm reg-staged fusion (which exposed load-use latency and
// doubled A re-read bytes: gemm 41 -> 61us). Keep the split.
__global__ void cast_all(const float* __restrict__ x, const float* __restrict__ Wq,
                         const float* __restrict__ Wk, const float* __restrict__ Wv,
                         u16* __restrict__ Xb, u16* __restrict__ Wc) {
  int idx = (blockIdx.x * 256 + threadIdx.x) * 4;
  const int NX = M_PIX * DIMC;
  const float* src;
  u16* dst;
  if (idx < NX) {
    src = x + idx; dst = Xb + idx;
  } else {
    int wi = idx - NX;
    if (wi >= NQKV * DIMC) return;
    int r = wi >> 9;
    int c = wi & 511;
    src = (r < 512)  ? (Wq + (size_t)r * 512 + c)
        : (r < 1024) ? (Wk + (size_t)(r - 512) * 512 + c)
                     : (Wv + (size_t)(r - 1024) * 512 + c);
    dst = Wc + wi;
  }
  float4 f = *(const float4*)src;
  uint32_t p0 = (uint32_t)f2bf(f.x) | ((uint32_t)f2bf(f.y) << 16);
  uint32_t p1 = (uint32_t)f2bf(f.z) | ((uint32_t)f2bf(f.w) << 16);
  *(uint2*)dst = make_uint2(p0, p1);
}

// ---- fused QKV GEMM (R19-verified): 128x128 BK=64, global_load_lds staging,
// XCD A-panel clustering, T2 swizzle both-sides (rule 21):
//   write: linear LDS dest; source column pre-swizzled ko=((c&3)^((c>>3)&3))*8
//   read:  slot = quad ^ ((l16>>1)&3)
__global__ __launch_bounds__(256, 4) void gemm_qkv(
    const u16* __restrict__ A, const u16* __restrict__ Bm,
    const float* __restrict__ bq, const float* __restrict__ bk,
    const float* __restrict__ bv, u16* __restrict__ qkv) {
  __shared__ u16 sA[2][128 * 32];
  __shared__ u16 sB[2][128 * 32];
  const int t = threadIdx.x;
  const int lane = t & 63;
  const int w = t >> 6;
  const int bid = blockIdx.x;
  const int g = (bid & 7) * 147 + (bid >> 3);   // bijective: 1176 = 8*147
  const int tile_m = (g / 12) * 128;
  const int tile_n = (g % 12) * 128;
  const int wm = (w & 1) * 64;
  const int wn = (w >> 1) * 64;
  const int quad = lane >> 4;
  const int l16 = lane & 15;

  f32x4 acc[4][4];
#pragma unroll
  for (int a = 0; a < 4; ++a)
#pragma unroll
    for (int bb = 0; bb < 4; ++bb) acc[a][bb] = (f32x4){0.f, 0.f, 0.f, 0.f};

  const int c0 = t, c1 = t + 256;
  const int r0 = c0 >> 2, ko0 = (((c0 & 3) ^ ((c0 >> 3) & 3))) * 8;  // swizzled src col
  const int r1 = c1 >> 2, ko1 = (((c1 & 3) ^ ((c1 >> 3) & 3))) * 8;
  const u16* gA0 = A + (size_t)(tile_m + r0) * DIMC + ko0;
  const u16* gA1 = A + (size_t)(tile_m + r1) * DIMC + ko1;
  const u16* gB0 = Bm + (size_t)(tile_n + r0) * DIMC + ko0;
  const u16* gB1 = Bm + (size_t)(tile_n + r1) * DIMC + ko1;
  const int ldsoff = (t & ~63) * 8;   // wave-uniform base; HW adds lane*16B

  for (int k0 = 0; k0 < DIMC; k0 += 64) {
#pragma unroll
    for (int h = 0; h < 2; ++h) {
      __builtin_amdgcn_global_load_lds(
          (const __attribute__((address_space(1))) void*)(gA0 + k0 + h * 32),
          (__attribute__((address_space(3))) void*)(sA[h] + 0 * 2048 + ldsoff), 16, 0, 0);
      __builtin_amdgcn_global_load_lds(
          (const __attribute__((address_space(1))) void*)(gA1 + k0 + h * 32),
          (__attribute__((address_space(3))) void*)(sA[h] + 1 * 2048 + ldsoff), 16, 0, 0);
      __builtin_amdgcn_global_load_lds(
          (const __attribute__((address_space(1))) void*)(gB0 + k0 + h * 32),
          (__attribute__((address_space(3))) void*)(sB[h] + 0 * 2048 + ldsoff), 16, 0, 0);
      __builtin_amdgcn_global_load_lds(
          (const __attribute__((address_space(1))) void*)(gB1 + k0 + h * 32),
          (__attribute__((address_space(3))) void*)(sB[h] + 1 * 2048 + ldsoff), 16, 0, 0);
    }
    __syncthreads();

    const int sw8 = (quad ^ ((l16 >> 1) & 3)) * 8;   // swizzled read slot
#pragma unroll
    for (int h = 0; h < 2; ++h) {
      bf16x8 af[4], bfr[4];
#pragma unroll
      for (int mt = 0; mt < 4; ++mt)
        af[mt] = *(const bf16x8*)(sA[h] + (wm + mt * 16 + l16) * 32 + sw8);
#pragma unroll
      for (int nt = 0; nt < 4; ++nt)
        bfr[nt] = *(const bf16x8*)(sB[h] + (wn + nt * 16 + l16) * 32 + sw8);
#pragma unroll
      for (int mt = 0; mt < 4; ++mt)
#pragma unroll
        for (int nt = 0; nt < 4; ++nt)
          acc[mt][nt] = __builtin_amdgcn_mfma_f32_16x16x32_bf16(bfr[nt], af[mt], acc[mt][nt], 0, 0, 0);
    }
    __syncthreads();
  }

  const float qscale = 0.17677669529663687f;  // 1/sqrt(32)
#pragma unroll
  for (int mt = 0; mt < 4; ++mt) {
    const int m = tile_m + wm + mt * 16 + l16;
#pragma unroll
    for (int nt = 0; nt < 4; ++nt) {
      const int n0 = tile_n + wn + nt * 16 + quad * 4;
      const int mat = n0 >> 9;
      const int cc = n0 & 511;
      const float* bias = (mat == 0) ? bq : (mat == 1) ? bk : bv;
      const float4 bv4 = *(const float4*)(bias + cc);
      const float scl = (mat == 0) ? qscale : 1.0f;
      u16 h0 = f2bf((acc[mt][nt][0] + bv4.x) * scl);
      u16 h1 = f2bf((acc[mt][nt][1] + bv4.y) * scl);
      u16 h2 = f2bf((acc[mt][nt][2] + bv4.z) * scl);
      u16 h3 = f2bf((acc[mt][nt][3] + bv4.w) * scl);
      uint2 pk = make_uint2((uint32_t)h0 | ((uint32_t)h1 << 16),
                            (uint32_t)h2 | ((uint32_t)h3 << 16));
      *(uint2*)(qkv + (size_t)mat * M_PIX * DIMC + (size_t)m * DIMC + cc) = pk;
    }
  }
}

// ---- neighborhood attention v12 (best-known): 8-row blocks, K/Q direct-to-
// reg, 9-chunk softmax, single barrier, setprio, rcp. ----
__global__ __launch_bounds__(512, 4) void natten_k(const u16* __restrict__ qkv,
                                                   const float* __restrict__ rpb,
                                                   float* __restrict__ out) {
  __shared__ u16 sP[8 * 2688];       // 43008 B, per-wave P tiles (PRIVATE per wave)
  __shared__ u16 sVt[32 * 296];      // 18944 B, [dim][cand], stride 296 u16
  __shared__ float sRpb[256];        // 169 real (pre-scaled by LOG2E) + zero pad
  __shared__ uint32_t sTbl[320];     // [parity][160]: c | (r'*13+c)<<8 ; 255 = invalid

  const int tid = threadIdx.x;
  const int lane = tid & 63;
  const int w = tid >> 6;            // 0..7: pixel row within block
  const int l16 = lane & 15;
  const int quad = lane >> 4;

  const int bid = blockIdx.x;
  const int xcd = bid & 7;
  const int idx = bid >> 3;          // 0..223
  const int head = idx / 14;
  const int gl = idx - head * 14;
  const int g = xcd * 14 + gl;       // 0..111
  const int jg = g & 3;
  const int gi = g >> 2;             // 0..27
  const int b = gi / 7;
  const int ig = gi - b * 7;
  const int i0 = ig * 8, j0 = jg * 14;
  int c0 = j0 - 3; c0 = c0 < 0 ? 0 : (c0 > 36 ? 36 : c0);
  int nib = i0 - 3; nib = nib < 0 ? 0 : (nib > 49 ? 49 : nib);

  const int iw = i0 + w;
  int niw = iw - 3; niw = niw < 0 ? 0 : (niw > 49 ? 49 : niw);
  const int rowoff = niw - nib;       // 0..7
  const int par = rowoff & 1;
  const int woff2 = rowoff * 20 - par * 4;   // 16B-aligned cand base, 0..136
  const int wconst = niw - iw + 6;

  const int qv = l16 < 14 ? l16 : 13;        // clamp pad queries for safe rpb idx
  const int jq = j0 + qv;
  int njq = jq - 3; njq = njq < 0 ? 0 : (njq > 49 ? 49 : njq);
  const uint32_t offq = (uint32_t)(njq - c0); // 0..13
  const int Cq = wconst * 13 + (c0 - jq + 6);

  const u16* Kpl = qkv + (size_t)M_PIX * DIMC;

  union { uint4 u; bf16x8 v; } qu;
  qu.u = make_uint4(0, 0, 0, 0);
  if (l16 < 14) {
    size_t qpx = (size_t)((b * 56 + iw) * 56 + j0 + l16);
    qu.u = *(const uint4*)(qkv + qpx * DIMC + head * 32 + quad * 8);
  }
  const bf16x8 qf = qu.v;

  if (tid < 296) {
    const int pair = tid >> 1, half = tid & 1;
    const int cand0 = pair * 2;
    int r = (cand0 * 205) >> 12;
    int c = cand0 - r * 20;
    int rimg = nib + r;
    const bool ok = (rimg < 56);
    size_t px = (size_t)((b * 56 + rimg) * 56 + c0 + c);
    const u16* vsrc = Kpl + (size_t)M_PIX * DIMC + px * DIMC + head * 32 + half * 16;
    u16* vt = sVt + cand0;
#pragma unroll
    for (int dgh = 0; dgh < 2; ++dgh) {
      uint4 va = ok ? *(const uint4*)(vsrc + dgh * 8) : make_uint4(0, 0, 0, 0);
      uint4 vb = ok ? *(const uint4*)(vsrc + DIMC + dgh * 8) : make_uint4(0, 0, 0, 0);
      int d0 = (half * 2 + dgh) * 8;
      *(uint32_t*)(vt + (d0 + 0) * 296) = __builtin_amdgcn_perm(vb.x, va.x, 0x05040100u);
      *(uint32_t*)(vt + (d0 + 1) * 296) = __builtin_amdgcn_perm(vb.x, va.x, 0x07060302u);
      *(uint32_t*)(vt + (d0 + 2) * 296) = __builtin_amdgcn_perm(vb.y, va.y, 0x05040100u);
      *(uint32_t*)(vt + (d0 + 3) * 296) = __builtin_amdgcn_perm(vb.y, va.y, 0x07060302u);
      *(uint32_t*)(vt + (d0 + 4) * 296) = __builtin_amdgcn_perm(vb.z, va.z, 0x05040100u);
      *(uint32_t*)(vt + (d0 + 5) * 296) = __builtin_amdgcn_perm(vb.z, va.z, 0x07060302u);
      *(uint32_t*)(vt + (d0 + 6) * 296) = __builtin_amdgcn_perm(vb.w, va.w, 0x05040100u);
      *(uint32_t*)(vt + (d0 + 7) * 296) = __builtin_amdgcn_perm(vb.w, va.w, 0x07060302u);
    }
  }
  const float LOG2E = 1.4426950408889634f;
  if (tid < 256) sRpb[tid] = (tid < 169) ? rpb[head * 169 + tid] * LOG2E : 0.f;
  if (tid < 320) {
    int pp = tid >= 160 ? 1 : 0;
    int s = tid - pp * 160;
    int t0 = s - pp * 4;
    uint32_t e = 255u;
    if (t0 >= 0 && t0 < 140) {
      int r = (t0 * 205) >> 12;
      int c = t0 - r * 20;
      e = (uint32_t)c | ((uint32_t)(r * 13 + c) << 8);
    }
    sTbl[tid] = e;
  }

  const int pxbase = (b * 56 + nib) * 56 + c0;   // cand(r,c) -> px = pxbase + r*56 + c
  const u16* kbase = Kpl + (size_t)head * 32 + quad * 8;
  bf16x8 kreg[9];
#pragma unroll
  for (int ch = 0; ch < 9; ++ch) {
    int cand = woff2 + ch * 16 + l16;
    int r = (cand * 205) >> 12;                  // cand/20, exact for cand<409
    int c = cand - r * 20;
    int px = pxbase + r * 56 + c;                // pad rows: in-allocation garbage, masked
    kreg[ch] = *(const bf16x8*)(kbase + (size_t)px * DIMC);
  }

  __syncthreads();   // publish sVt/sRpb/sTbl; K loads still in flight

  u16* sPw = sP + w * 2688;
  f32x4 S[9];
  __builtin_amdgcn_s_setprio(1);
#pragma unroll
  for (int ch = 0; ch < 9; ++ch)
    S[ch] = __builtin_amdgcn_mfma_f32_16x16x32_bf16(kreg[ch], qf, (f32x4){0.f, 0.f, 0.f, 0.f}, 0, 0, 0);
  __builtin_amdgcn_s_setprio(0);

  float l = 0.f;
  const uint32_t* tb = sTbl + par * 160;
#pragma unroll
  for (int ch = 0; ch < 9; ++ch) {
    uint4 te = *(const uint4*)(tb + ch * 16 + quad * 4);
    float pv[4];
    uint32_t es[4] = {te.x, te.y, te.z, te.w};
#pragma unroll
    for (int rg = 0; rg < 4; ++rg) {
      uint32_t e = es[rg];
      uint32_t ce = e & 255u;
      bool valid = (ce - offq) < 7u;           // unsigned window test
      int ridx = (int)((e >> 8) & 255u) + Cq;  // invalid -> Cq (pad zero, safe)
      float rbl = sRpb[ridx];                  // pre-scaled by LOG2E
      float p = exp2f(__builtin_fmaf(S[ch][rg], LOG2E, rbl));
      p = valid ? p : 0.f;
      pv[rg] = p;
      l += p;
    }
    uint32_t plo, phi;
    asm("v_cvt_pk_bf16_f32 %0, %1, %2" : "=v"(plo) : "v"(pv[0]), "v"(pv[1]));
    asm("v_cvt_pk_bf16_f32 %0, %1, %2" : "=v"(phi) : "v"(pv[2]), "v"(pv[3]));
    *(uint2*)((char*)sPw + l16 * 336 + ch * 32 + quad * 8) = make_uint2(plo, phi);
  }
  // chunk 9 (slots 144..159): always invalid -> P = 0
  *(uint2*)((char*)sPw + l16 * 336 + 9 * 32 + quad * 8) = make_uint2(0u, 0u);
  l += __shfl_xor(l, 16);
  l += __shfl_xor(l, 32);

  // P round trip is SAME-WAVE (sPw private): drain DS queue, pin reads below
  // the wait (rule 18).
  asm volatile("s_waitcnt lgkmcnt(0)" ::: "memory");
  __builtin_amdgcn_sched_barrier(0);

  f32x4 O0 = (f32x4){0.f, 0.f, 0.f, 0.f};
  f32x4 O1 = (f32x4){0.f, 0.f, 0.f, 0.f};
  __builtin_amdgcn_s_setprio(1);
#pragma unroll
  for (int c32 = 0; c32 < 5; ++c32) {
    bf16x8 pf = *(const bf16x8*)((char*)sPw + l16 * 336 + c32 * 64 + quad * 16);
    bf16x8 v0 = *(const bf16x8*)((char*)sVt + (0 + l16) * 592 + woff2 * 2 + c32 * 64 + quad * 16);
    bf16x8 v1 = *(const bf16x8*)((char*)sVt + (16 + l16) * 592 + woff2 * 2 + c32 * 64 + quad * 16);
    O0 = __builtin_amdgcn_mfma_f32_16x16x32_bf16(v0, pf, O0, 0, 0, 0);
    O1 = __builtin_amdgcn_mfma_f32_16x16x32_bf16(v1, pf, O1, 0, 0, 0);
  }
  __builtin_amdgcn_s_setprio(0);

  if (l16 < 14) {
    const float inv = __builtin_amdgcn_rcpf(l);   // bf16-level tolerance: rcp safe
    float* op = out + ((size_t)((b * 56 + iw) * 56 + j0 + l16)) * DIMC + head * 32;
    *(float4*)(op + quad * 4) =
        make_float4(O0[0] * inv, O0[1] * inv, O0[2] * inv, O0[3] * inv);
    *(float4*)(op + 16 + quad * 4) =
        make_float4(O1[0] * inv, O1[1] * inv, O1[2] * inv, O1[3] * inv);
  }
}

extern "C" void kernel_launch(void* const* d_in, const int* in_sizes, int n_in,
                              void* d_out, int out_size, void* d_ws, size_t ws_size,
                              hipStream_t stream) {
  const float* x   = (const float*)d_in[0];
  const float* Wq  = (const float*)d_in[1];
  const float* bq  = (const float*)d_in[2];
  const float* Wk  = (const float*)d_in[3];
  const float* bk  = (const float*)d_in[4];
  const float* Wv  = (const float*)d_in[5];
  const float* bv  = (const float*)d_in[6];
  const float* rpb = (const float*)d_in[7];
  float* out = (float*)d_out;

  u16* Xb  = (u16*)d_ws;
  u16* Wc  = Xb + (size_t)M_PIX * DIMC;
  u16* qkv = Wc + (size_t)NQKV * DIMC;

  const int ncast = (M_PIX * DIMC + NQKV * DIMC) / 4;
  cast_all<<<(ncast + 255) / 256, 256, 0, stream>>>(x, Wq, Wk, Wv, Xb, Wc);
  gemm_qkv<<<1176, 256, 0, stream>>>(Xb, Wc, bq, bk, bv, qkv);  // 8*147, T2-swizzled LDS
  natten_k<<<1792, 512, 0, stream>>>(qkv, rpb, out);            // v12 (best-known)
}